// Round 5
// baseline (90.309 us; speedup 1.0000x reference)
//
#include <hip/hip_runtime.h>

// CMDNet (M=2, m={-1,+1}, equal alpha) — MFMA HH + 8-waves/SIMD edition.
// Block = 256 threads = 4 waves, barrier-free; each wave owns 2 batches.
// lane = h*32 + k (h = batch-half, k = symbol).
//
// Phase 1: HH = Ht^T Ht per batch via v_mfma_f32_32x32x16_bf16 with bf16
//   hi/lo split (err ~2^-17). Same regs as A and B => k-permutation cancels.
// Phase 2: redistribute D (C/D: col=lane&31, row=(j&3)+8*(j>>2)+4*(lane>>5))
//   so lane (h,k) holds full HH_h[k][*] via shfl_xor(32).
// Phase 3: 64 iterations; xt exchanged through LDS in MFMA-row order.
//
// __launch_bounds__(256,8): VGPR cap 64. The MFMA version needs only ~56
// (R4 measured), so 8 waves/SIMD now fits without spill — R4 at (256,4) was
// latency-bound (Occupancy 38%, VALUBusy 52%). Tripwire: if FETCH_SIZE
// explodes past ~70 MB, the cap spilled (R2/R3 signature) -> revert to 4.

#define NRX 64
#define KSYM 32

typedef float  f32x16 __attribute__((ext_vector_type(16)));
typedef short  short8 __attribute__((ext_vector_type(8)));

__device__ __forceinline__ float readlane_f(float v, int lane) {
    return __int_as_float(__builtin_amdgcn_readlane(__float_as_int(v), lane));
}
__device__ __forceinline__ unsigned cvt_pk_bf16(float a, float b) {
    unsigned r;
    asm("v_cvt_pk_bf16_f32 %0, %1, %2" : "=v"(r) : "v"(a), "v"(b));
    return r;   // low16 = bf16(a), high16 = bf16(b), RNE
}

union FragU { unsigned u[4]; short8 s; };

__global__ __launch_bounds__(256, 8) void cmdnet_kernel(
    const float* __restrict__ yt,      // [B,64]
    const float* __restrict__ Ht,      // [B,64,32]
    const float* __restrict__ sigmat0, // [B]
    const float* __restrict__ taui,    // [niter+1]
    const float* __restrict__ delta,   // [niter]
    float* __restrict__ out_ft,        // [B,32,2]
    float* __restrict__ out_xt,        // [B,32]
    int niter)
{
    __shared__ __align__(16) float ytL[4][2][NRX];   // 2 KB
    __shared__ __align__(16) float xtP[4][2][KSYM];  // 1 KB, MFMA-row order

    const int tid  = threadIdx.x;
    const int w    = tid >> 6;
    const int lane = tid & 63;
    const int k    = lane & 31;
    const int h    = lane >> 5;
    const int hi8  = h * 8;
    const int bb   = blockIdx.x * 8 + w * 2;
    const int b    = bb + h;

    ytL[w][0][lane] = yt[(size_t)bb * NRX + lane];
    ytL[w][1][lane] = yt[(size_t)bb * NRX + NRX + lane];

    float dreg = 0.f, treg = 1.f;
    if (lane < niter) { dreg = delta[lane]; treg = fabsf(taui[lane + 1]); }

    float sig2 = sigmat0[b];
    sig2 *= sig2;

    // ---- Phase 1: MFMA HH (+ yH VALU partials) ----
    f32x16 acc0, acc1;
    #pragma unroll
    for (int j = 0; j < 16; ++j) { acc0[j] = 0.f; acc1[j] = 0.f; }
    float yhp0 = 0.f, yhp1 = 0.f;

    #pragma unroll
    for (int s = 0; s < 2; ++s) {
        const float* Hb = Ht + ((size_t)(bb + s)) * (NRX * KSYM);
        #pragma unroll
        for (int c = 0; c < 4; ++c) {
            const float* base = Hb + (c * 16 + hi8) * KSYM + k;
            float f[8];
            #pragma unroll
            for (int e = 0; e < 8; ++e) f[e] = base[e * KSYM];

            float4 ya = *reinterpret_cast<const float4*>(&ytL[w][s][c * 16 + hi8]);
            float4 yb = *reinterpret_cast<const float4*>(&ytL[w][s][c * 16 + hi8 + 4]);
            float yp = (s == 0) ? yhp0 : yhp1;
            yp = fmaf(ya.x, f[0], yp); yp = fmaf(ya.y, f[1], yp);
            yp = fmaf(ya.z, f[2], yp); yp = fmaf(ya.w, f[3], yp);
            yp = fmaf(yb.x, f[4], yp); yp = fmaf(yb.y, f[5], yp);
            yp = fmaf(yb.z, f[6], yp); yp = fmaf(yb.w, f[7], yp);
            if (s == 0) yhp0 = yp; else yhp1 = yp;

            FragU hiF, loF;
            #pragma unroll
            for (int p = 0; p < 4; ++p) {
                unsigned hp = cvt_pk_bf16(f[2*p], f[2*p+1]);
                float h0 = __uint_as_float(hp << 16);
                float h1 = __uint_as_float(hp & 0xffff0000u);
                float l0 = f[2*p]   - h0;
                float l1 = f[2*p+1] - h1;
                hiF.u[p] = hp;
                loF.u[p] = cvt_pk_bf16(l0, l1);
            }
            if (s == 0) {
                acc0 = __builtin_amdgcn_mfma_f32_32x32x16_bf16(hiF.s, hiF.s, acc0, 0, 0, 0);
                acc0 = __builtin_amdgcn_mfma_f32_32x32x16_bf16(hiF.s, loF.s, acc0, 0, 0, 0);
                acc0 = __builtin_amdgcn_mfma_f32_32x32x16_bf16(loF.s, hiF.s, acc0, 0, 0, 0);
            } else {
                acc1 = __builtin_amdgcn_mfma_f32_32x32x16_bf16(hiF.s, hiF.s, acc1, 0, 0, 0);
                acc1 = __builtin_amdgcn_mfma_f32_32x32x16_bf16(hiF.s, loF.s, acc1, 0, 0, 0);
                acc1 = __builtin_amdgcn_mfma_f32_32x32x16_bf16(loF.s, hiF.s, acc1, 0, 0, 0);
            }
        }
    }

    float yh0 = yhp0 + __shfl_xor(yhp0, 32, 64);
    float yh1 = yhp1 + __shfl_xor(yhp1, 32, 64);
    float yh  = h ? yh1 : yh0;

    // ---- Phase 2: lane (h,k) <- full row k of its batch ----
    float own[16], oth[16];
    #pragma unroll
    for (int j = 0; j < 16; ++j) {
        float t = h ? acc1[j] : acc0[j];
        float u = h ? acc0[j] : acc1[j];
        own[j] = t;
        oth[j] = __shfl_xor(u, 32, 64);
    }

    // ---- Phase 3: iterations ----
    float tau = fabsf(taui[0]);
    float G0 = 0.f, G1 = 0.f;
    float ft0 = 0.5f, ft1 = 0.5f, xt = 0.f;

    const int pos = ((k >> 2) & 1) * 16 + (k & 3) + ((k >> 3) << 2);
    const float4* xo = reinterpret_cast<const float4*>(&xtP[w][h][h * 16]);
    const float4* xx = reinterpret_cast<const float4*>(&xtP[w][h][(1 ^ h) * 16]);

    for (int i = 0; i < niter; ++i) {
        xtP[w][h][pos] = xt;

        float d        = readlane_f(dreg, i);
        float tau_next = readlane_f(treg, i);

        float a0 = -yh, a1 = 0.f, a2 = 0.f, a3 = 0.f;
        #pragma unroll
        for (int t = 0; t < 4; ++t) {
            float4 xa = xo[t];
            float4 xb = xx[t];
            a0 = fmaf(own[4*t+0], xa.x, a0);
            a1 = fmaf(own[4*t+1], xa.y, a1);
            a2 = fmaf(own[4*t+2], xa.z, a2);
            a3 = fmaf(own[4*t+3], xa.w, a3);
            a0 = fmaf(oth[4*t+0], xb.x, a0);
            a1 = fmaf(oth[4*t+1], xb.y, a1);
            a2 = fmaf(oth[4*t+2], xb.z, a2);
            a3 = fmaf(oth[4*t+3], xb.w, a3);
        }
        float r = (a0 + a1) + (a2 + a3);

        float p  = 2.f * tau * ft0 * ft1 * r;
        float e0 = __expf(-G0);
        float e1 = __expf(-G1);
        float g0 = fmaf(sig2, 1.f - e0, -p);
        float g1 = fmaf(sig2, 1.f - e1,  p);
        G0 = fmaf(-d, g0, G0);
        G1 = fmaf(-d, g1, G1);

        tau = tau_next;
        float z  = tau * (G1 - G0);
        float ez = __expf(-fabsf(z));
        float sg = __builtin_amdgcn_rcpf(1.f + ez);
        float abig = sg, asml = ez * sg;
        bool ps = (z >= 0.f);
        ft1 = ps ? abig : asml;
        ft0 = ps ? asml : abig;
        xt  = ft1 - ft0;
    }

    // ---- outputs ----
    float2 f2 = make_float2(ft0, ft1);
    reinterpret_cast<float2*>(out_ft)[(size_t)b * KSYM + k] = f2;
    out_xt[(size_t)b * KSYM + k] = xt;
}

extern "C" void kernel_launch(void* const* d_in, const int* in_sizes, int n_in,
                              void* d_out, int out_size, void* d_ws, size_t ws_size,
                              hipStream_t stream) {
    const float* yt    = (const float*)d_in[0];
    const float* Ht    = (const float*)d_in[1];
    const float* sg    = (const float*)d_in[2];
    const float* taui  = (const float*)d_in[3];
    const float* delta = (const float*)d_in[4];
    int B     = in_sizes[2];
    int niter = in_sizes[4];
    float* out    = (float*)d_out;
    float* out_ft = out;
    float* out_xt = out + (size_t)B * 64;

    dim3 grid(B / 8), block(256);
    hipLaunchKernelGGL(cmdnet_kernel, grid, block, 0, stream,
                       yt, Ht, sg, taui, delta, out_ft, out_xt, niter);
}

// Round 6
// 87.738 us; speedup vs baseline: 1.0293x; 1.0293x over previous
//
#include <hip/hip_runtime.h>

// CMDNet (M=2, m={-1,+1}, equal alpha) — MFMA HH + DPP-diagonal matvec.
// Block = 256 = 4 waves, barrier-free; each wave owns 2 batches.
// lane = h*32 + k. DPP rows (16 lanes) align with k&16 blocks per half.
//
// Phase 1: HH = Ht^T Ht per batch via v_mfma_f32_32x32x16_bf16, bf16 hi/lo
//   split (err ~2^-17). yH via VALU partials on the same loads.
// Phase 2: acc (C/D layout: col=lane&31, row=(j&3)+8*(j>>2)+4*(lane>>5)) is
//   written to a per-wave LDS buffer, then re-gathered DIAGONALLY:
//   own_d[j]    = HH[k][ (k&16)     | perm_j(k&15) ]
//   own_d[16+j] = HH[k][ ((k&16)^16)| perm_j(k&15) ]
//   where perm_j is PROBED with the same update_dpp ctrl used in the loop —
//   setup and loop agree by construction regardless of ror direction.
// Phase 3: 64 iterations, ZERO LDS reads in the matvec (R5 diagnosis: the
//   8x ds_read_b128/iter xt re-broadcast was the wall, ~82us of DS-pipe time).
//   Step j: a += dpp_ror:j(xt) * own_d[j]; other 16-block via one
//   shfl_xor(xt,16) then same 15 DPP steps.
//
// __launch_bounds__(256,4): VGPR cap 128. R2/R3/R5 lesson: asking >4
// waves/EU forces <=64 regs and spills (FETCH/WRITE explosion signature).

#define NRX 64
#define KSYM 32

typedef float  f32x16 __attribute__((ext_vector_type(16)));
typedef short  short8 __attribute__((ext_vector_type(8)));

__device__ __forceinline__ float readlane_f(float v, int lane) {
    return __int_as_float(__builtin_amdgcn_readlane(__float_as_int(v), lane));
}
__device__ __forceinline__ unsigned cvt_pk_bf16(float a, float b) {
    unsigned r;
    asm("v_cvt_pk_bf16_f32 %0, %1, %2" : "=v"(r) : "v"(a), "v"(b));
    return r;   // low16 = bf16(a), high16 = bf16(b), RNE
}
template <int N>
__device__ __forceinline__ float dpp_ror_f(float v) {
    return __int_as_float(__builtin_amdgcn_update_dpp(
        0, __float_as_int(v), 0x120 + N, 0xF, 0xF, true));
}
template <int N>
__device__ __forceinline__ int dpp_ror_i(int v) {
    return __builtin_amdgcn_update_dpp(0, v, 0x120 + N, 0xF, 0xF, true);
}

union FragU { unsigned u[4]; short8 s; };

__global__ __launch_bounds__(256, 4) void cmdnet_kernel(
    const float* __restrict__ yt,      // [B,64]
    const float* __restrict__ Ht,      // [B,64,32]
    const float* __restrict__ sigmat0, // [B]
    const float* __restrict__ taui,    // [niter+1]
    const float* __restrict__ delta,   // [niter]
    float* __restrict__ out_ft,        // [B,32,2]
    float* __restrict__ out_xt,        // [B,32]
    int niter)
{
    __shared__ __align__(16) float hhbuf[4][KSYM * KSYM];  // 16 KB: per-wave HH buffer
    __shared__ __align__(16) float ytL[4][2][NRX];         // 2 KB

    const int tid  = threadIdx.x;
    const int w    = tid >> 6;
    const int lane = tid & 63;
    const int k    = lane & 31;
    const int h    = lane >> 5;
    const int hi8  = h * 8;
    const int bb   = blockIdx.x * 8 + w * 2;
    const int b    = bb + h;

    ytL[w][0][lane] = yt[(size_t)bb * NRX + lane];
    ytL[w][1][lane] = yt[(size_t)bb * NRX + NRX + lane];

    float dreg = 0.f, treg = 1.f;
    if (lane < niter) { dreg = delta[lane]; treg = fabsf(taui[lane + 1]); }

    float sig2 = sigmat0[b];
    sig2 *= sig2;

    // ---- Phase 1: MFMA HH (+ yH VALU partials) ----
    f32x16 acc0, acc1;
    #pragma unroll
    for (int j = 0; j < 16; ++j) { acc0[j] = 0.f; acc1[j] = 0.f; }
    float yhp0 = 0.f, yhp1 = 0.f;

    #pragma unroll
    for (int s = 0; s < 2; ++s) {
        const float* Hb = Ht + ((size_t)(bb + s)) * (NRX * KSYM);
        #pragma unroll
        for (int c = 0; c < 4; ++c) {
            const float* base = Hb + (c * 16 + hi8) * KSYM + k;
            float f[8];
            #pragma unroll
            for (int e = 0; e < 8; ++e) f[e] = base[e * KSYM];

            float4 ya = *reinterpret_cast<const float4*>(&ytL[w][s][c * 16 + hi8]);
            float4 yb = *reinterpret_cast<const float4*>(&ytL[w][s][c * 16 + hi8 + 4]);
            float yp = (s == 0) ? yhp0 : yhp1;
            yp = fmaf(ya.x, f[0], yp); yp = fmaf(ya.y, f[1], yp);
            yp = fmaf(ya.z, f[2], yp); yp = fmaf(ya.w, f[3], yp);
            yp = fmaf(yb.x, f[4], yp); yp = fmaf(yb.y, f[5], yp);
            yp = fmaf(yb.z, f[6], yp); yp = fmaf(yb.w, f[7], yp);
            if (s == 0) yhp0 = yp; else yhp1 = yp;

            FragU hiF, loF;
            #pragma unroll
            for (int p = 0; p < 4; ++p) {
                unsigned hp = cvt_pk_bf16(f[2*p], f[2*p+1]);
                float h0 = __uint_as_float(hp << 16);
                float h1 = __uint_as_float(hp & 0xffff0000u);
                loF.u[p] = cvt_pk_bf16(f[2*p] - h0, f[2*p+1] - h1);
                hiF.u[p] = hp;
            }
            if (s == 0) {
                acc0 = __builtin_amdgcn_mfma_f32_32x32x16_bf16(hiF.s, hiF.s, acc0, 0, 0, 0);
                acc0 = __builtin_amdgcn_mfma_f32_32x32x16_bf16(hiF.s, loF.s, acc0, 0, 0, 0);
                acc0 = __builtin_amdgcn_mfma_f32_32x32x16_bf16(loF.s, hiF.s, acc0, 0, 0, 0);
            } else {
                acc1 = __builtin_amdgcn_mfma_f32_32x32x16_bf16(hiF.s, hiF.s, acc1, 0, 0, 0);
                acc1 = __builtin_amdgcn_mfma_f32_32x32x16_bf16(hiF.s, loF.s, acc1, 0, 0, 0);
                acc1 = __builtin_amdgcn_mfma_f32_32x32x16_bf16(loF.s, hiF.s, acc1, 0, 0, 0);
            }
        }
    }

    float yh0 = yhp0 + __shfl_xor(yhp0, 32, 64);
    float yh1 = yhp1 + __shfl_xor(yhp1, 32, 64);
    float yh  = h ? yh1 : yh0;

    // ---- Phase 2: LDS roundtrip -> diagonal-permuted rows own_d[32] ----
    // Pass s: all 64 lanes write acc_s (full 32x32 HH_s), lanes h==s gather.
    // Same-wave DS ops are in-order; buffer aliasing keeps compiler honest.
    float own_d[32];
    const int low4 = k & 15;
    float* buf = &hhbuf[w][0];
    #pragma unroll
    for (int s = 0; s < 2; ++s) {
        #pragma unroll
        for (int j = 0; j < 16; ++j) {
            int row = (j & 3) + 8 * (j >> 2) + 4 * h;
            buf[row * 32 + k] = s ? acc1[j] : acc0[j];
        }
        if (h == s) {
            const float* rowp = buf + k * 32;
            own_d[0]  = rowp[k];          // j=0: identity, col=k (diagonal)
            own_d[16] = rowp[k ^ 16];     // j=16: identity on swapped block
            #define GATH(J) { \
                int idx = dpp_ror_i<J>(low4); \
                own_d[J]        = rowp[(k & 16) | idx]; \
                own_d[16 + (J)] = rowp[((k & 16) ^ 16) | idx]; }
            GATH(1)  GATH(2)  GATH(3)  GATH(4)  GATH(5)
            GATH(6)  GATH(7)  GATH(8)  GATH(9)  GATH(10)
            GATH(11) GATH(12) GATH(13) GATH(14) GATH(15)
            #undef GATH
        }
    }

    // ---- Phase 3: iterations — matvec fully in registers via DPP ----
    float tau = fabsf(taui[0]);
    float G0 = 0.f, G1 = 0.f;
    float ft0 = 0.5f, ft1 = 0.5f, xt = 0.f;

    for (int i = 0; i < niter; ++i) {
        float d        = readlane_f(dreg, i);
        float tau_next = readlane_f(treg, i);

        float xts = __shfl_xor(xt, 16, 64);   // other 16-block of this batch
        float a[4];
        a[0] = fmaf(own_d[0], xt, -yh);
        a[1] = own_d[16] * xts;
        a[2] = 0.f; a[3] = 0.f;
        #define STEP(J) { \
            float ra = dpp_ror_f<J>(xt); \
            float rb = dpp_ror_f<J>(xts); \
            a[(J) & 3]       = fmaf(own_d[J],        ra, a[(J) & 3]); \
            a[((J) + 2) & 3] = fmaf(own_d[16 + (J)], rb, a[((J) + 2) & 3]); }
        STEP(1)  STEP(2)  STEP(3)  STEP(4)  STEP(5)
        STEP(6)  STEP(7)  STEP(8)  STEP(9)  STEP(10)
        STEP(11) STEP(12) STEP(13) STEP(14) STEP(15)
        #undef STEP
        float r = (a[0] + a[1]) + (a[2] + a[3]);

        float p  = 2.f * tau * ft0 * ft1 * r;
        float e0 = __expf(-G0);
        float e1 = __expf(-G1);
        float g0 = fmaf(sig2, 1.f - e0, -p);
        float g1 = fmaf(sig2, 1.f - e1,  p);
        G0 = fmaf(-d, g0, G0);
        G1 = fmaf(-d, g1, G1);

        tau = tau_next;
        float z  = tau * (G1 - G0);
        float ez = __expf(-fabsf(z));
        float sg = __builtin_amdgcn_rcpf(1.f + ez);
        float abig = sg, asml = ez * sg;
        bool ps = (z >= 0.f);
        ft1 = ps ? abig : asml;
        ft0 = ps ? asml : abig;
        xt  = ft1 - ft0;
    }

    // ---- outputs ----
    float2 f2 = make_float2(ft0, ft1);
    reinterpret_cast<float2*>(out_ft)[(size_t)b * KSYM + k] = f2;
    out_xt[(size_t)b * KSYM + k] = xt;
}

extern "C" void kernel_launch(void* const* d_in, const int* in_sizes, int n_in,
                              void* d_out, int out_size, void* d_ws, size_t ws_size,
                              hipStream_t stream) {
    const float* yt    = (const float*)d_in[0];
    const float* Ht    = (const float*)d_in[1];
    const float* sg    = (const float*)d_in[2];
    const float* taui  = (const float*)d_in[3];
    const float* delta = (const float*)d_in[4];
    int B     = in_sizes[2];
    int niter = in_sizes[4];
    float* out    = (float*)d_out;
    float* out_ft = out;
    float* out_xt = out + (size_t)B * 64;

    dim3 grid(B / 8), block(256);
    hipLaunchKernelGGL(cmdnet_kernel, grid, block, 0, stream,
                       yt, Ht, sg, taui, delta, out_ft, out_xt, niter);
}